// Round 6
// baseline (1353.316 us; speedup 1.0000x reference)
//
#include <hip/hip_runtime.h>
#include <hip/hip_bf16.h>
#include <math.h>
#include <stdint.h>

// Problem constants
#define N_TOK   8192          // SL*BS
#define HS      1024
#define FFN     4096
#define NE      8
#define NA      16384         // N_TOK * TOPK
#define CAP     16384         // per-expert bucket capacity (worst case)
#define BM      256
#define MAXT    72            // max total M-tiles: 16384/256 + 8
#define PERMSZ  16777216ULL   // NA * HS floats

typedef __attribute__((ext_vector_type(8))) short          bf16x8;
typedef __attribute__((ext_vector_type(4))) float          f32x4;
typedef __attribute__((ext_vector_type(4))) float          fvec4;
typedef __attribute__((ext_vector_type(4))) unsigned short usvec4;

__device__ __forceinline__ void gl_lds16(const void* g, void* l) {
  __builtin_amdgcn_global_load_lds(
      (const __attribute__((address_space(1))) unsigned int*)g,
      (__attribute__((address_space(3))) unsigned int*)l,
      16, 0, 0);
}

__device__ __forceinline__ unsigned short f2bf(float f) {
  union { float f; unsigned int u; } v; v.f = f;
  unsigned int r = v.u + 0x7FFFu + ((v.u >> 16) & 1u);
  return (unsigned short)(r >> 16);
}

// ---------------- conversion kernels ----------------

__global__ void cvt_x_kernel(const fvec4* __restrict__ in, unsigned short* __restrict__ out, int n4) {
  int i = blockIdx.x * 256 + threadIdx.x;
  if (i >= n4) return;
  fvec4 v = in[i];
  usvec4 o;
  o[0] = f2bf(v[0]); o[1] = f2bf(v[1]); o[2] = f2bf(v[2]); o[3] = f2bf(v[3]);
  *(usvec4*)(out + (size_t)i * 4) = o;
}

// in [E][R][C] f32 -> out [E][C][R] bf16 (K-contiguous B^T layout for GEMM)
__global__ void tpose_cvt_kernel(const float* __restrict__ in, unsigned short* __restrict__ out,
                                 int R, int C) {
  __shared__ float t[64][65];
  int bc = blockIdx.x * 64, br = blockIdx.y * 64, e = blockIdx.z;
  const float* ine = in + (size_t)e * R * C;
  unsigned short* oute = out + (size_t)e * R * C;
  int tx = threadIdx.x & 63, ty = threadIdx.x >> 6;   // ty in [0,4)
#pragma unroll
  for (int q = 0; q < 16; ++q) {
    int r = ty * 16 + q;
    t[r][tx] = ine[(size_t)(br + r) * C + bc + tx];
  }
  __syncthreads();
#pragma unroll
  for (int q = 0; q < 16; ++q) {
    int c = ty * 16 + q;
    oute[(size_t)(bc + c) * R + br + tx] = f2bf(t[tx][c]);
  }
}

// ---------------- routing ----------------

__global__ void route_kernel(const int* __restrict__ idx, const float* __restrict__ wts,
                             int* __restrict__ counts, int* __restrict__ btok,
                             int* __restrict__ bslot, float* __restrict__ bw) {
  int a = blockIdx.x * 256 + threadIdx.x;
  if (a >= NA) return;
  int e = idx[a];
  int pos = atomicAdd(&counts[e], 1);
  btok[(size_t)e * CAP + pos]  = a >> 1;     // token id
  bslot[(size_t)e * CAP + pos] = a;          // destination slot in perm buffer
  bw[(size_t)e * CAP + pos]    = wts[a];
}

__global__ void build_tiles_kernel(int* __restrict__ counts, int2* __restrict__ table) {
  if (threadIdx.x == 0 && blockIdx.x == 0) {
    int nt = 0;
    for (int e = 0; e < NE; ++e) {
      int c = counts[e];
      int t = (c + BM - 1) >> 8;
      for (int m = 0; m < t && nt < MAXT; ++m) table[nt++] = make_int2(e, m);
    }
    counts[8] = nt;
  }
}

// ---------------- grouped GEMM: 4 waves, per-wave 128x128, 3-buf counted-vmcnt ----------------
// Tile 256x256, BK=32. Per wave per K-tile: 16 ds_read_b128 feed 64 MFMA (ratio 0.25);
// one s_barrier + one vmcnt(8) per K-tile. LDS: 3 x 32KB, XOR-swizzle
// (k_byte ^= ((row>>1)&3)<<4) applied to both the pre-swizzled gl_lds source and reads.
// acc[8][8] (256 f32) lives in AGPRs; __launch_bounds__(256,1) gives the 512-reg budget.
// EPI=0: h=gelu(gather(x)@w1), kq=0.  EPI=1: perm[kq][slot]=w*(h@w2) with split-K=2.
template <int EPI, int KROW, int NT>
__global__ __launch_bounds__(256, 1)
void moe_gemm(const unsigned short* __restrict__ Ab,   // xb (EPI=0) or h (EPI=1)
              const unsigned short* __restrict__ Bb,   // w1T / w2T, [E][N][K] bf16
              unsigned short* __restrict__ hout,       // EPI=0 output
              float* __restrict__ perm,                // EPI=1 output (2 buffers of PERMSZ)
              const int* __restrict__ btok,
              const int* __restrict__ bslot,
              const float* __restrict__ bw,
              const int* __restrict__ counts,
              const int2* __restrict__ table,
              int p0, int tc) {
  constexpr int BUFSZ = 32768;             // A 256x32 (16KB) + B 256x32 (16KB)
  constexpr int SPT = (EPI == 0) ? 16 : 8; // sub-blocks per tile (g1: 16 nblk; g2: 4 nblk x 2 kq)
  __shared__ char lds[3 * BUFSZ];

  // Tile-clustered decode: tile j on XCD j&7; its SPT consumer blocks are
  // consecutive slots on that XCD (A-panel L2 reuse).
  int bid = blockIdx.x;
  int xcd = bid & 7, slot = bid >> 3;
  int j = xcd + 8 * (slot / SPT);
  int r0 = slot % SPT;
  int kq  = (EPI == 0) ? 0 : (r0 >> 2);
  int bn0 = (EPI == 0) ? r0 * 256 : (r0 & 3) * 256;
  int kbyte0 = kq * (NT * 64);             // split-K byte offset within a row

  int nt = counts[8];
  if (j < p0 || j >= p0 + tc || j >= nt) return;
  int2 te = table[j];
  int e = te.x, tm = te.y;
  int count = counts[e];
  int slotb = j - p0;

  int tid = threadIdx.x;
  int wid = tid >> 6, lane = tid & 63;
  int wm = wid >> 1, wn = wid & 1;

  const unsigned short* Be = Bb + (size_t)e * ((size_t)FFN * HS);

  // ---- staging setup: 32 chunks of 1KB (16 rows x 64B), 8 per wave ----
  const char* src[8];
  int dst[8];
#pragma unroll
  for (int q = 0; q < 8; ++q) {
    int c = wid * 8 + q;
    int rr = (c < 16 ? c * 16 : (c - 16) * 16) + (lane >> 2);
    int klog = ((lane & 3) * 16) ^ (((rr >> 1) & 3) << 4);
    if (c < 16) {          // A chunk
      dst[q] = c * 1024;
      if (EPI == 0) {
        int grow = tm * BM + rr;
        int tok = (grow < count) ? btok[(size_t)e * CAP + grow] : 0;
        src[q] = (const char*)(Ab + (size_t)tok * KROW) + kbyte0 + klog;
      } else {
        src[q] = (const char*)(Ab + ((size_t)slotb * BM + rr) * KROW) + kbyte0 + klog;
      }
    } else {               // B chunk
      dst[q] = 16384 + (c - 16) * 1024;
      src[q] = (const char*)(Be + (size_t)(bn0 + rr) * KROW) + kbyte0 + klog;
    }
  }

  // ---- fragment read offsets (swizzled) ----
  int rA = wm * 128 + (lane & 15);
  int rB = wn * 128 + (lane & 15);
  int ks = (lane >> 4) * 16;
  int offA0 = rA * 64 + (ks ^ (((rA >> 1) & 3) << 4));
  int offB0 = 16384 + rB * 64 + (ks ^ (((rB >> 1) & 3) << 4));

  f32x4 acc[8][8] = {};

  // ---- prologue: stage kt0 -> buf0, kt1 -> buf1 ----
#pragma unroll
  for (int q = 0; q < 8; ++q) gl_lds16(src[q], lds + dst[q]);
#pragma unroll
  for (int q = 0; q < 8; ++q) gl_lds16(src[q] + 64, lds + BUFSZ + dst[q]);

  int bi = 0;
  for (int t = 0; t < NT; ++t) {
    // own kt-t loads landed (kt t+1's 8 may stay in flight)
    asm volatile("s_waitcnt vmcnt(8)" ::: "memory");
    __builtin_amdgcn_sched_barrier(0);
    __builtin_amdgcn_s_barrier();   // all waves: kt t visible; buf (t+2)%3 free
    __builtin_amdgcn_sched_barrier(0);

    int kt2 = t + 2; if (kt2 >= NT) kt2 -= NT;   // wrap re-stage keeps vmcnt uniform
    int bi2 = bi + 2; if (bi2 >= 3) bi2 -= 3;
    char* db = lds + bi2 * BUFSZ;
#pragma unroll
    for (int q = 0; q < 8; ++q)
      gl_lds16(src[q] + (size_t)kt2 * 64, db + dst[q]);

    const char* rbuf = lds + bi * BUFSZ;
    bf16x8 a[8], b[8];
#pragma unroll
    for (int n = 0; n < 8; ++n) b[n] = *(const bf16x8*)(rbuf + offB0 + n * 1024);
    a[0] = *(const bf16x8*)(rbuf + offA0);
    a[1] = *(const bf16x8*)(rbuf + offA0 + 1024);
    __builtin_amdgcn_s_setprio(1);
#pragma unroll
    for (int i = 0; i < 8; ++i) {
      if (i < 6) a[i + 2] = *(const bf16x8*)(rbuf + offA0 + (i + 2) * 1024);
#pragma unroll
      for (int n = 0; n < 8; ++n)
        acc[i][n] = __builtin_amdgcn_mfma_f32_16x16x32_bf16(a[i], b[n], acc[i][n], 0, 0, 0);
    }
    __builtin_amdgcn_s_setprio(0);
    ++bi; if (bi >= 3) bi = 0;
  }
  asm volatile("s_waitcnt vmcnt(0)" ::: "memory");  // drain wrap re-stages

  // ---- epilogue ----
  if (EPI == 0) {
    size_t hb = (size_t)slotb * BM;
#pragma unroll
    for (int i = 0; i < 8; ++i) {
      int row = wm * 128 + i * 16 + ((lane >> 4) << 2);
#pragma unroll
      for (int n = 0; n < 8; ++n) {
        int col = bn0 + wn * 128 + n * 16 + (lane & 15);
#pragma unroll
        for (int rr = 0; rr < 4; ++rr) {
          float v = acc[i][n][rr];
          // gelu(v) = v * sigmoid(2u), u = 0.79788456 v (1 + 0.044715 v^2)
          float x2 = v * v;
          float u2 = 1.5957691216057308f * v * fmaf(0.044715f, x2, 1.0f);
          u2 = fminf(fmaxf(u2, -30.f), 30.f);
          float ee = __expf(u2);
          float g = v * __fdividef(ee, ee + 1.0f);
          hout[(hb + row + rr) * FFN + col] = f2bf(g);
        }
      }
    }
  } else {
    float* pq = perm + (size_t)kq * PERMSZ;
#pragma unroll
    for (int i = 0; i < 8; ++i) {
      int rowb = wm * 128 + i * 16 + ((lane >> 4) << 2);
#pragma unroll
      for (int rr = 0; rr < 4; ++rr) {
        int grow = tm * BM + rowb + rr;
        if (grow < count) {
          int s = bslot[(size_t)e * CAP + grow];
          float wgt = bw[(size_t)e * CAP + grow];
#pragma unroll
          for (int n = 0; n < 8; ++n) {
            int col = bn0 + wn * 128 + n * 16 + (lane & 15);
            pq[(size_t)s * HS + col] = wgt * acc[i][n][rr];
          }
        }
      }
    }
  }
}

// ---------------- combine: out[t] = sum over 2 slots x 2 K-halves ----------------
__global__ void combine_kernel(const fvec4* __restrict__ perm, fvec4* __restrict__ out, int n4) {
  int i = blockIdx.x * 256 + threadIdx.x;
  if (i >= n4) return;
  int t = i >> 8;            // HS/4 = 256 fvec4 per row
  int c = i & 255;
  const fvec4* p0 = perm;
  const fvec4* p1 = perm + PERMSZ / 4;
  size_t r0 = (size_t)(2 * t) * 256 + c;
  size_t r1 = (size_t)(2 * t + 1) * 256 + c;
  out[i] = (p0[r0] + p1[r0]) + (p0[r1] + p1[r1]);
}

// ---------------- host ----------------

extern "C" void kernel_launch(void* const* d_in, const int* in_sizes, int n_in,
                              void* d_out, int out_size, void* d_ws, size_t ws_size,
                              hipStream_t stream) {
  const float* x   = (const float*)d_in[0];
  const float* ew  = (const float*)d_in[1];
  // d_in[2] = scores (unused by reference output)
  const float* w1  = (const float*)d_in[3];
  const float* w2  = (const float*)d_in[4];
  const int*   eix = (const int*)d_in[5];

  char* ws = (char*)d_ws;
  const size_t o_w1T    = 0;                       // 67,108,864
  const size_t o_w2T    = 67108864ULL;             // 67,108,864
  const size_t o_xb     = 134217728ULL;            // 16,777,216
  const size_t o_btok   = 150994944ULL;            // 524,288
  const size_t o_bslot  = 151519232ULL;            // 524,288
  const size_t o_bw     = 152043520ULL;            // 524,288
  const size_t o_counts = 152567808ULL;            // 256
  const size_t o_table  = 152568064ULL;            // 1,280
  const size_t o_perm   = 152569344ULL;            // 2 x 67,108,864
  const size_t o_h      = 286787072ULL;            // up to 150,994,944

  unsigned short* w1T = (unsigned short*)(ws + o_w1T);
  unsigned short* w2T = (unsigned short*)(ws + o_w2T);
  unsigned short* xb  = (unsigned short*)(ws + o_xb);
  int*   btok   = (int*)(ws + o_btok);
  int*   bslot  = (int*)(ws + o_bslot);
  float* bw     = (float*)(ws + o_bw);
  int*   counts = (int*)(ws + o_counts);
  int2*  table  = (int2*)(ws + o_table);
  float* perm   = (float*)(ws + o_perm);
  unsigned short* hbuf = (unsigned short*)(ws + o_h);

  // h-buffer chunking if workspace is small
  long long havail = (long long)ws_size - (long long)o_h;
  long long tile_bytes = (long long)BM * FFN * 2;   // 2 MB per M-tile
  int tc = (int)(havail / tile_bytes);
  if (tc < 1) tc = 1;
  if (tc > MAXT) tc = MAXT;
  int npass = (MAXT + tc - 1) / tc;

  hipMemsetAsync(counts, 0, 256, stream);

  cvt_x_kernel<<<(N_TOK * HS / 4 + 255) / 256, 256, 0, stream>>>(
      (const fvec4*)x, xb, N_TOK * HS / 4);
  tpose_cvt_kernel<<<dim3(FFN / 64, HS / 64, NE), 256, 0, stream>>>(w1, w1T, HS, FFN);
  tpose_cvt_kernel<<<dim3(HS / 64, FFN / 64, NE), 256, 0, stream>>>(w2, w2T, FFN, HS);

  route_kernel<<<(NA + 255) / 256, 256, 0, stream>>>(eix, ew, counts, btok, bslot, bw);
  build_tiles_kernel<<<1, 64, 0, stream>>>(counts, table);

  for (int p = 0; p < npass; ++p) {
    // GEMM1: 256x256 tile, 4 waves, K=1024 -> 16 N-blocks * 72 tiles = 1152 blocks
    moe_gemm<0, HS, HS / 32><<<dim3(MAXT * 16), 256, 0, stream>>>(
        xb, w1T, hbuf, perm, btok, bslot, bw, counts, table, p * tc, tc);
    // GEMM2: 256x256 tile, 4 waves, split-K=2 (NT=64 each) -> 8 sub * 72 tiles = 576 blocks
    moe_gemm<1, FFN, FFN / 64><<<dim3(MAXT * 8), 256, 0, stream>>>(
        hbuf, w2T, hbuf, perm, btok, bslot, bw, counts, table, p * tc, tc);
  }

  combine_kernel<<<(N_TOK * HS / 4 + 255) / 256, 256, 0, stream>>>(
      (const fvec4*)perm, (fvec4*)d_out, N_TOK * HS / 4);
}

// Round 7
// 615.285 us; speedup vs baseline: 2.1995x; 2.1995x over previous
//
#include <hip/hip_runtime.h>
#include <hip/hip_bf16.h>
#include <math.h>
#include <stdint.h>

// Problem constants
#define N_TOK   8192          // SL*BS
#define HS      1024
#define FFN     4096
#define NE      8
#define NA      16384         // N_TOK * TOPK
#define CAP     16384         // per-expert bucket capacity (worst case)
#define BM      256
#define MAXT    72            // max total M-tiles: 16384/256 + 8

typedef __attribute__((ext_vector_type(8))) short          bf16x8;
typedef __attribute__((ext_vector_type(4))) float          f32x4;
typedef __attribute__((ext_vector_type(4))) float          fvec4;
typedef __attribute__((ext_vector_type(4))) unsigned short usvec4;

__device__ __forceinline__ void gl_lds16(const void* g, void* l) {
  __builtin_amdgcn_global_load_lds(
      (const __attribute__((address_space(1))) unsigned int*)g,
      (__attribute__((address_space(3))) unsigned int*)l,
      16, 0, 0);
}

__device__ __forceinline__ unsigned short f2bf(float f) {
  union { float f; unsigned int u; } v; v.f = f;
  unsigned int r = v.u + 0x7FFFu + ((v.u >> 16) & 1u);
  return (unsigned short)(r >> 16);
}

// ---------------- conversion kernels ----------------

__global__ void cvt_x_kernel(const fvec4* __restrict__ in, unsigned short* __restrict__ out, int n4) {
  int i = blockIdx.x * 256 + threadIdx.x;
  if (i >= n4) return;
  fvec4 v = in[i];
  usvec4 o;
  o[0] = f2bf(v[0]); o[1] = f2bf(v[1]); o[2] = f2bf(v[2]); o[3] = f2bf(v[3]);
  *(usvec4*)(out + (size_t)i * 4) = o;
}

// in [E][R][C] f32 -> out [E][C][R] bf16 (K-contiguous B^T layout for GEMM)
__global__ void tpose_cvt_kernel(const float* __restrict__ in, unsigned short* __restrict__ out,
                                 int R, int C) {
  __shared__ float t[64][65];
  int bc = blockIdx.x * 64, br = blockIdx.y * 64, e = blockIdx.z;
  const float* ine = in + (size_t)e * R * C;
  unsigned short* oute = out + (size_t)e * R * C;
  int tx = threadIdx.x & 63, ty = threadIdx.x >> 6;   // ty in [0,4)
#pragma unroll
  for (int q = 0; q < 16; ++q) {
    int r = ty * 16 + q;
    t[r][tx] = ine[(size_t)(br + r) * C + bc + tx];
  }
  __syncthreads();
#pragma unroll
  for (int q = 0; q < 16; ++q) {
    int c = ty * 16 + q;
    oute[(size_t)(bc + c) * R + br + tx] = f2bf(t[tx][c]);
  }
}

// ---------------- routing ----------------

__global__ void route_kernel(const int* __restrict__ idx, const float* __restrict__ wts,
                             int* __restrict__ counts, int* __restrict__ btok,
                             int* __restrict__ bslot, float* __restrict__ bw) {
  int a = blockIdx.x * 256 + threadIdx.x;
  if (a >= NA) return;
  int e = idx[a];
  int pos = atomicAdd(&counts[e], 1);
  btok[(size_t)e * CAP + pos]  = a >> 1;     // token id
  bslot[(size_t)e * CAP + pos] = a;          // destination slot in perm buffer
  bw[(size_t)e * CAP + pos]    = wts[a];
}

__global__ void build_tiles_kernel(int* __restrict__ counts, int2* __restrict__ table) {
  if (threadIdx.x == 0 && blockIdx.x == 0) {
    int nt = 0;
    for (int e = 0; e < NE; ++e) {
      int c = counts[e];
      int t = (c + BM - 1) >> 8;
      for (int m = 0; m < t && nt < MAXT; ++m) table[nt++] = make_int2(e, m);
    }
    counts[8] = nt;
  }
}

// ---------------- grouped GEMM: 256x256 tile, 8 waves, BK=64, 2-slab dbuf ----------------
// Per slab (BK=64): stage 8 gl_lds (slab t+1) -> compiler-scheduled {ds_read, 64 MFMA}
// -> vmcnt(0) (free: covered by ~5k cyc compute) + ONE barrier. Per-wave 128x64,
// acc[8][4]. XOR swizzle: kbyte ^= (row&7)<<4 within the 128B slab-row (pre-swizzled
// gl_lds source + swizzled ds_read). Epilogue: per-wave LDS repack -> vector stores.
template <int EPI, int KDIM>
__global__ __launch_bounds__(512, 2)
void moe_gemm(const unsigned short* __restrict__ Ab,   // xb (EPI=0) or h (EPI=1)
              const unsigned short* __restrict__ Bb,   // w1T / w2T, [E][N][K] bf16
              unsigned short* __restrict__ hout,       // EPI=0 output
              float* __restrict__ perm,                // EPI=1 output
              const int* __restrict__ btok,
              const int* __restrict__ bslot,
              const float* __restrict__ bw,
              const int* __restrict__ counts,
              const int2* __restrict__ table,
              int p0, int tc) {
  constexpr int NCOLS = (EPI == 0) ? (FFN / 256) : (HS / 256);  // 16 / 4
  constexpr int NSLAB = KDIM / 64;
  constexpr int SLABSZ = 65536;            // A 256x64x2B (32KB) + B 32KB

  __shared__ char lds[2 * SLABSZ];

  // tile-major grid: consecutive blocks share the A panel; whole-GEMM window
  // keeps B (<=64MB) L3-resident.
  int bid = blockIdx.x;
  int j = bid / NCOLS;
  int bn0 = (bid % NCOLS) * 256;

  int nt = counts[8];
  if (j < p0 || j >= p0 + tc || j >= nt) return;
  int2 te = table[j];
  int e = te.x, tm = te.y;
  int count = counts[e];
  int slotb = j - p0;

  int tid = threadIdx.x;
  int wid = tid >> 6, lane = tid & 63;
  int wm = wid >> 2, wn = wid & 3;         // 2M x 4N wave grid

  const unsigned short* Be = Bb + (size_t)e * ((size_t)FFN * HS);

  // ---- staging: 64 chunks of 1KB (8 rows x 128B); 8 per wave ----
  const char* src[8];
  int dst[8];
  int lrow8 = lane >> 3;                                    // row-in-chunk 0..7
  int klog = ((lane & 7) * 16) ^ (lrow8 << 4);              // pre-swizzled k-byte
#pragma unroll
  for (int q = 0; q < 8; ++q) {
    int c = wid * 8 + q;                  // 0..63
    dst[q] = c * 1024;
    if (c < 32) {         // A rows c*8 + lrow8
      int row = c * 8 + lrow8;
      if (EPI == 0) {
        int grow = tm * BM + row;
        int tok = (grow < count) ? btok[(size_t)e * CAP + grow] : 0;
        src[q] = (const char*)(Ab + (size_t)tok * KDIM) + klog;
      } else {
        src[q] = (const char*)(Ab + ((size_t)slotb * BM + row) * KDIM) + klog;
      }
    } else {              // B rows (c-32)*8 + lrow8
      int nrow = bn0 + (c - 32) * 8 + lrow8;
      src[q] = (const char*)(Be + (size_t)nrow * KDIM) + klog;
    }
  }

  // ---- fragment read offsets (swizzled; row stride 128B) ----
  int rA = wm * 128 + (lane & 15);
  int rB = wn * 64 + (lane & 15);
  int ksw = (lane >> 4) * 16;
  int swz = (lane & 7) << 4;
  int offA[2], offB[2];
#pragma unroll
  for (int kk = 0; kk < 2; ++kk) {
    offA[kk] = rA * 128 + ((kk * 64 + ksw) ^ swz);
    offB[kk] = 32768 + rB * 128 + ((kk * 64 + ksw) ^ swz);
  }

  f32x4 acc[8][4] = {};

  // ---- prologue: stage slab 0 -> buf 0 ----
#pragma unroll
  for (int q = 0; q < 8; ++q) gl_lds16(src[q], lds + dst[q]);
  asm volatile("s_waitcnt vmcnt(0)" ::: "memory");
  __builtin_amdgcn_s_barrier();
  __builtin_amdgcn_sched_barrier(0);

  for (int t = 0; t < NSLAB; ++t) {
    char* rbuf = lds + (t & 1) * SLABSZ;
    char* db   = lds + ((t + 1) & 1) * SLABSZ;
    if (t + 1 < NSLAB) {
#pragma unroll
      for (int q = 0; q < 8; ++q)
        gl_lds16(src[q] + (size_t)(t + 1) * 128, db + dst[q]);
    }
#pragma unroll
    for (int kk = 0; kk < 2; ++kk) {
      bf16x8 a[8], b[4];
#pragma unroll
      for (int n = 0; n < 4; ++n) b[n] = *(const bf16x8*)(rbuf + offB[kk] + n * 2048);
#pragma unroll
      for (int i = 0; i < 8; ++i) a[i] = *(const bf16x8*)(rbuf + offA[kk] + i * 2048);
#pragma unroll
      for (int i = 0; i < 8; ++i)
#pragma unroll
        for (int n = 0; n < 4; ++n)
          acc[i][n] = __builtin_amdgcn_mfma_f32_16x16x32_bf16(a[i], b[n], acc[i][n], 0, 0, 0);
    }
    __builtin_amdgcn_sched_barrier(0);
    asm volatile("s_waitcnt vmcnt(0)" ::: "memory");   // slab t+1 landed (covered by compute)
    __builtin_amdgcn_s_barrier();
    __builtin_amdgcn_sched_barrier(0);
  }

  // ---- epilogue: per-wave LDS repack (8KB region) -> vector global stores ----
  char* wlds = lds + wid * 8192;           // 32 rows x 256B (f32)
  int l15 = lane & 15, l16 = lane >> 4;
#pragma unroll
  for (int p = 0; p < 4; ++p) {
    // write pass-p quadrants (rows p*32 .. p*32+31 of the wave's 128)
#pragma unroll
    for (int ii = 0; ii < 2; ++ii) {
      int i = p * 2 + ii;
#pragma unroll
      for (int n = 0; n < 4; ++n) {
        int waddr = (ii * 16 + l16 * 4) * 256 + (n * 16 + l15) * 4;
#pragma unroll
        for (int rr = 0; rr < 4; ++rr)
          *(float*)(wlds + waddr + rr * 256) = acc[i][n][rr];
      }
    }
    asm volatile("s_waitcnt lgkmcnt(0)" ::: "memory");
    __builtin_amdgcn_sched_barrier(0);
    // readback: 4 col-contiguous values per lane -> vector store
#pragma unroll
    for (int rd = 0; rd < 8; ++rd) {
      int row = rd * 4 + l16;              // 0..31
      f32x4 v = *(const f32x4*)(wlds + row * 256 + l15 * 16);
      int col = bn0 + wn * 64 + l15 * 4;
      if (EPI == 0) {
        usvec4 o;
#pragma unroll
        for (int z = 0; z < 4; ++z) {
          float vv = v[z];
          float x2 = vv * vv;
          float u2 = 1.5957691216057308f * vv * fmaf(0.044715f, x2, 1.0f);
          u2 = fminf(fmaxf(u2, -30.f), 30.f);
          float ee = __expf(u2);
          o[z] = f2bf(vv * __fdividef(ee, ee + 1.0f));
        }
        size_t hrow = (size_t)slotb * BM + wm * 128 + p * 32 + row;
        *(usvec4*)(hout + hrow * FFN + col) = o;
      } else {
        int grow = tm * BM + wm * 128 + p * 32 + row;
        if (grow < count) {
          int s = bslot[(size_t)e * CAP + grow];
          float wgt = bw[(size_t)e * CAP + grow];
          fvec4 o;
#pragma unroll
          for (int z = 0; z < 4; ++z) o[z] = wgt * v[z];
          *(fvec4*)(perm + (size_t)s * HS + col) = o;
        }
      }
    }
    __builtin_amdgcn_sched_barrier(0);
  }
}

// ---------------- combine: out[t] = perm[2t] + perm[2t+1] ----------------
__global__ void combine_kernel(const fvec4* __restrict__ perm, fvec4* __restrict__ out, int n4) {
  int i = blockIdx.x * 256 + threadIdx.x;
  if (i >= n4) return;
  int t = i >> 8;            // HS/4 = 256 fvec4 per row
  int c = i & 255;
  out[i] = perm[(size_t)(2 * t) * 256 + c] + perm[(size_t)(2 * t + 1) * 256 + c];
}

// ---------------- host ----------------

extern "C" void kernel_launch(void* const* d_in, const int* in_sizes, int n_in,
                              void* d_out, int out_size, void* d_ws, size_t ws_size,
                              hipStream_t stream) {
  const float* x   = (const float*)d_in[0];
  const float* ew  = (const float*)d_in[1];
  // d_in[2] = scores (unused by reference output)
  const float* w1  = (const float*)d_in[3];
  const float* w2  = (const float*)d_in[4];
  const int*   eix = (const int*)d_in[5];

  char* ws = (char*)d_ws;
  const size_t o_w1T    = 0;                       // 67,108,864
  const size_t o_w2T    = 67108864ULL;             // 67,108,864
  const size_t o_xb     = 134217728ULL;            // 16,777,216
  const size_t o_btok   = 150994944ULL;            // 524,288
  const size_t o_bslot  = 151519232ULL;            // 524,288
  const size_t o_bw     = 152043520ULL;            // 524,288
  const size_t o_counts = 152567808ULL;            // 256
  const size_t o_table  = 152568064ULL;            // 1,280
  const size_t o_perm   = 152569344ULL;            // 67,108,864
  const size_t o_h      = 219678208ULL;            // up to 150,994,944

  unsigned short* w1T = (unsigned short*)(ws + o_w1T);
  unsigned short* w2T = (unsigned short*)(ws + o_w2T);
  unsigned short* xb  = (unsigned short*)(ws + o_xb);
  int*   btok   = (int*)(ws + o_btok);
  int*   bslot  = (int*)(ws + o_bslot);
  float* bw     = (float*)(ws + o_bw);
  int*   counts = (int*)(ws + o_counts);
  int2*  table  = (int2*)(ws + o_table);
  float* perm   = (float*)(ws + o_perm);
  unsigned short* hbuf = (unsigned short*)(ws + o_h);

  // h-buffer chunking if workspace is small
  long long havail = (long long)ws_size - (long long)o_h;
  long long tile_bytes = (long long)BM * FFN * 2;   // 2 MB per M-tile
  int tc = (int)(havail / tile_bytes);
  if (tc < 1) tc = 1;
  if (tc > MAXT) tc = MAXT;
  int npass = (MAXT + tc - 1) / tc;

  hipMemsetAsync(counts, 0, 256, stream);

  cvt_x_kernel<<<(N_TOK * HS / 4 + 255) / 256, 256, 0, stream>>>(
      (const fvec4*)x, xb, N_TOK * HS / 4);
  tpose_cvt_kernel<<<dim3(FFN / 64, HS / 64, NE), 256, 0, stream>>>(w1, w1T, HS, FFN);
  tpose_cvt_kernel<<<dim3(HS / 64, FFN / 64, NE), 256, 0, stream>>>(w2, w2T, FFN, HS);

  route_kernel<<<(NA + 255) / 256, 256, 0, stream>>>(eix, ew, counts, btok, bslot, bw);
  build_tiles_kernel<<<1, 64, 0, stream>>>(counts, table);

  for (int p = 0; p < npass; ++p) {
    // GEMM1: 256x256, 8 waves, K=1024 (16 slabs) -> 72 tiles x 16 cols = 1152 blocks
    moe_gemm<0, HS><<<dim3(MAXT * 16), 512, 0, stream>>>(
        xb, w1T, hbuf, perm, btok, bslot, bw, counts, table, p * tc, tc);
    // GEMM2: 256x256, 8 waves, K=4096 (64 slabs) -> 72 tiles x 4 cols = 288 blocks (~1 round)
    moe_gemm<1, FFN><<<dim3(MAXT * 4), 512, 0, stream>>>(
        hbuf, w2T, hbuf, perm, btok, bslot, bw, counts, table, p * tc, tc);
  }

  combine_kernel<<<(N_TOK * HS / 4 + 255) / 256, 256, 0, stream>>>(
      (const fvec4*)perm, (fvec4*)d_out, N_TOK * HS / 4);
}